// Round 8
// baseline (93.307 us; speedup 1.0000x reference)
//
#include <hip/hip_runtime.h>
#include <math.h>

#define BB 16
#define TT 2048
#define DD 256
#define KK 8
#define TILE 16      // tokens per block-tile (phase1: 4/wave, phase2: all 16)
static constexpr float LN_EPS = 1e-5f;

// DPP lane exchange (VALU pipe). 0xB1=quad_perm xor1, 0x4E=quad_perm xor2,
// 0x108=row_shl:8, 0x118=row_shr:8 (16-lane rows, zero-fill via bound_ctrl).
template<int CTRL>
__device__ __forceinline__ float dppf(float x) {
    return __int_as_float(__builtin_amdgcn_update_dpp(
        0, __float_as_int(x), CTRL, 0xF, 0xF, true));
}

// ---------------------------------------------------------------------------
// Two-phase fused kernel. Phase-1 network is the R5-verified one (v mapped to
// lane bits {0,1,4}); R8 change: tokens processed in PAIRS so two independent
// butterfly chains overlap (latency hiding by ILP, not by network surgery —
// R6/R7's remapped network NaN'd and is abandoned).
// ---------------------------------------------------------------------------
__global__ __launch_bounds__(256, 3) void lde_fused4(
    const float* __restrict__ x,
    const float* __restrict__ centers,
    const float* __restrict__ scale,
    const float* __restrict__ temperature,
    float* __restrict__ ws_wx,   // [BB*C][KK*512] (0..255 wx | 256..511 wx2)
    float* __restrict__ ws_w,    // [BB*C][KK]
    int C, int NT)               // NT = tiles per block = (TT/C)/TILE
{
    const int c    = blockIdx.x;
    const int b    = blockIdx.y;
    const int tid  = threadIdx.x;
    const int wave = tid >> 6;       // 0..3
    const int lane = tid & 63;

    __shared__ float wbuf[TILE * KK];   // 512 B: tile weights, true k-order

    // Per-lane center fragments with -2*temp*scale folded in.
    const float4* cv = reinterpret_cast<const float4*>(centers);
    const float temp = temperature[0];
    float4 c4s[KK]; float A[KK], Bc[KK];
    #pragma unroll
    for (int k = 0; k < KK; ++k) {
        const float4 cc = cv[k * 64 + lane];
        const float a = temp * scale[k];
        A[k]  = a;
        Bc[k] = a * (cc.x*cc.x + cc.y*cc.y + cc.z*cc.z + cc.w*cc.w);
        const float na = -2.0f * a;
        c4s[k] = make_float4(na*cc.x, na*cc.y, na*cc.z, na*cc.w);
    }

    const int bit0 = lane & 1;
    const int bit1 = (lane >> 1) & 1;
    const int bit4 = (lane >> 4) & 1;
    const int v    = (bit0 << 2) | (bit1 << 1) | bit4;  // lane's cluster id
    const bool writer = ((lane & 44) == 0);  // lanes 0-3,16-19: v covers 0..7

    // Phase-2 accumulators: clusters kA=2*wave, kB=2*wave+1. 18 regs.
    float4 axA = {0,0,0,0}, ax2A = {0,0,0,0};
    float4 axB = {0,0,0,0}, ax2B = {0,0,0,0};
    float  aw0 = 0.0f, aw1 = 0.0f;

    const int TC = NT * TILE;                 // tokens per block
    const float4* xr = reinterpret_cast<const float4*>(x + (size_t)b * TT * DD);

    for (int tile = 0; tile < NT; ++tile) {
        const int tb = c * TC + tile * TILE;

        // ---------------- Phase 1: weights, 2 tokens in flight per wave
        #pragma unroll
        for (int j = 0; j < TILE / 4; j += 2) {
            const int tA = wave * (TILE / 4) + j;
            const int tB = tA + 1;
            const float4 cxA = xr[(size_t)(tb + tA) * 64 + lane];
            const float4 cxB = xr[(size_t)(tb + tB) * 64 + lane];

            const float x2A = fmaf(cxA.x,cxA.x, fmaf(cxA.y,cxA.y,
                              fmaf(cxA.z,cxA.z, cxA.w*cxA.w)));
            const float x2B = fmaf(cxB.x,cxB.x, fmaf(cxB.y,cxB.y,
                              fmaf(cxB.z,cxB.z, cxB.w*cxB.w)));
            float qA[KK], qB[KK];
            #pragma unroll
            for (int k = 0; k < KK; ++k) {
                const float rA = fmaf(cxA.x,c4s[k].x, fmaf(cxA.y,c4s[k].y,
                                 fmaf(cxA.z,c4s[k].z, cxA.w*c4s[k].w)));
                qA[k] = rA + fmaf(A[k], x2A, Bc[k]);
                const float rB = fmaf(cxB.x,c4s[k].x, fmaf(cxB.y,c4s[k].y,
                                 fmaf(cxB.z,c4s[k].z, cxB.w*c4s[k].w)));
                qB[k] = rB + fmaf(A[k], x2B, Bc[k]);
            }

            // R5-verified halving reduce: bit0 (qp xor1), bit1 (qp xor2),
            // bit4 (shfl_xor 16) — run for both tokens (independent chains).
            float SA, SB;
            #pragma unroll
            for (int tok = 0; tok < 2; ++tok) {
                const float* q = tok ? qB : qA;
                float a0, a1, a2, a3;
                {
                    const float s_0 = bit0 ? q[0] : q[4];
                    const float s_1 = bit0 ? q[1] : q[5];
                    const float s_2 = bit0 ? q[2] : q[6];
                    const float s_3 = bit0 ? q[3] : q[7];
                    const float k_0 = bit0 ? q[4] : q[0];
                    const float k_1 = bit0 ? q[5] : q[1];
                    const float k_2 = bit0 ? q[6] : q[2];
                    const float k_3 = bit0 ? q[7] : q[3];
                    a0 = k_0 + dppf<0xB1>(s_0);
                    a1 = k_1 + dppf<0xB1>(s_1);
                    a2 = k_2 + dppf<0xB1>(s_2);
                    a3 = k_3 + dppf<0xB1>(s_3);
                }
                float b0, b1;
                {
                    const float s_0 = bit1 ? a0 : a2;
                    const float s_1 = bit1 ? a1 : a3;
                    const float k_0 = bit1 ? a2 : a0;
                    const float k_1 = bit1 ? a3 : a1;
                    b0 = k_0 + dppf<0x4E>(s_0);
                    b1 = k_1 + dppf<0x4E>(s_1);
                }
                float S;
                {
                    const float s_ = bit4 ? b0 : b1;
                    const float k_ = bit4 ? b1 : b0;
                    S = k_ + __shfl_xor(s_, 16, 64);
                }
                // broadcast-reduce lane bits 2, 3, 5
                S += __shfl_xor(S, 4, 64);
                S += dppf<0x108>(S) + dppf<0x118>(S);
                S += __shfl_xor(S, 32, 64);
                if (tok) SB = S; else SA = S;
            }

            // own-cluster softmax weights (R5-verified butterflies)
            float wnA, wnB;
            #pragma unroll
            for (int tok = 0; tok < 2; ++tok) {
                const float S = tok ? SB : SA;
                float mn = S;
                mn = fminf(mn, dppf<0xB1>(mn));
                mn = fminf(mn, dppf<0x4E>(mn));
                mn = fminf(mn, __shfl_xor(mn, 16, 64));
                const float e = __expf(mn - S);
                float den = e;
                den += dppf<0xB1>(den);
                den += dppf<0x4E>(den);
                den += __shfl_xor(den, 16, 64);
                const float wn = e / den;
                if (tok) wnB = wn; else wnA = wn;
            }

            if (writer) {
                wbuf[tA * KK + v] = wnA;
                wbuf[tB * KK + v] = wnB;
            }
        }
        __syncthreads();

        // ---------------- Phase 2: accumulate 2 clusters/wave over tile
        #pragma unroll 4
        for (int t = 0; t < TILE; ++t) {
            const float4 cx = xr[(size_t)(tb + t) * 64 + lane];   // L1-hot
            const float2 wk = *reinterpret_cast<const float2*>(
                                  &wbuf[t * KK + 2 * wave]);      // LDS broadcast
            aw0 += wk.x;  aw1 += wk.y;
            const float xx0 = cx.x*cx.x, xx1 = cx.y*cx.y;
            const float xx2 = cx.z*cx.z, xx3 = cx.w*cx.w;
            axA.x  = fmaf(wk.x, cx.x, axA.x);   axA.y  = fmaf(wk.x, cx.y, axA.y);
            axA.z  = fmaf(wk.x, cx.z, axA.z);   axA.w  = fmaf(wk.x, cx.w, axA.w);
            ax2A.x = fmaf(wk.x, xx0, ax2A.x);   ax2A.y = fmaf(wk.x, xx1, ax2A.y);
            ax2A.z = fmaf(wk.x, xx2, ax2A.z);   ax2A.w = fmaf(wk.x, xx3, ax2A.w);
            axB.x  = fmaf(wk.y, cx.x, axB.x);   axB.y  = fmaf(wk.y, cx.y, axB.y);
            axB.z  = fmaf(wk.y, cx.z, axB.z);   axB.w  = fmaf(wk.y, cx.w, axB.w);
            ax2B.x = fmaf(wk.y, xx0, ax2B.x);   ax2B.y = fmaf(wk.y, xx1, ax2B.y);
            ax2B.z = fmaf(wk.y, xx2, ax2B.z);   ax2B.w = fmaf(wk.y, xx3, ax2B.w);
        }
        __syncthreads();   // before next tile overwrites wbuf
    }

    // Epilogue: each wave exclusively owns clusters 2w,2w+1 -> direct stores.
    const size_t base = (size_t)(b * C + c) * (KK * 512);
    const int kA = 2 * wave, kB = 2 * wave + 1;
    *reinterpret_cast<float4*>(ws_wx + base + kA*512       + 4*lane) = axA;
    *reinterpret_cast<float4*>(ws_wx + base + kA*512 + 256 + 4*lane) = ax2A;
    *reinterpret_cast<float4*>(ws_wx + base + kB*512       + 4*lane) = axB;
    *reinterpret_cast<float4*>(ws_wx + base + kB*512 + 256 + 4*lane) = ax2B;
    if (lane == 0) {
        ws_w[(size_t)(b * C + c) * KK + kA] = aw0;
        ws_w[(size_t)(b * C + c) * KK + kB] = aw1;
    }
}

// ---------------------------------------------------------------------------
// Final: per (b,k). 1024 threads, 8 chunk-octets sum in parallel, then
// mean/var (reference decomposition) + layernorm over 512, write out.
// ---------------------------------------------------------------------------
__global__ __launch_bounds__(1024) void lde_final4(
    const float* __restrict__ ws_wx,
    const float* __restrict__ ws_w,
    const float* __restrict__ centers,
    float* __restrict__ out,
    int C)
{
    const int b   = blockIdx.x >> 3;
    const int k   = blockIdx.x & 7;
    const int tid = threadIdx.x;
    const int oct = tid >> 7;
    const int j   = tid & 127;

    const float4* base = reinterpret_cast<const float4*>(ws_wx);
    float ax = 0.f, ay = 0.f, az = 0.f, aw = 0.f;
    for (int ci = oct; ci < C; ci += 8) {
        const float4 vv = base[((size_t)((b * C + ci) * KK + k)) * 128 + j];
        ax += vv.x; ay += vv.y; az += vv.z; aw += vv.w;
    }

    __shared__ float4 part[1024];
    __shared__ float  sum[512];
    __shared__ float  swbuf[64];
    part[tid] = make_float4(ax, ay, az, aw);
    if (tid >= 512 && tid < 512 + C)
        swbuf[tid - 512] = ws_w[(size_t)(b * C + (tid - 512)) * KK + k];
    __syncthreads();

    if (tid < 128) {
        float4 t = part[tid];
        #pragma unroll
        for (int o = 1; o < 8; ++o) {
            const float4 u = part[o * 128 + tid];
            t.x += u.x; t.y += u.y; t.z += u.z; t.w += u.w;
        }
        reinterpret_cast<float4*>(sum)[tid] = t;
    }
    __syncthreads();

    if (tid < 256) {
        float sw = 0.0f;
        for (int ci = 0; ci < C; ++ci) sw += swbuf[ci];
        const int d = tid;
        const float wx   = sum[d];
        const float wx2  = sum[256 + d];
        const float ck   = centers[k * DD + d];
        const float mean = wx - ck * sw;
        const float E    = wx2 - 2.0f * ck * wx + ck * ck * sw;
        const float var  = E - mean * mean;
        sum[d]       = mean;
        sum[256 + d] = var;
    }
    __syncthreads();

    float val = (tid < 512) ? sum[tid] : 0.0f;
    float s1 = val, s2 = val * val;
    #pragma unroll
    for (int off = 32; off >= 1; off >>= 1) {
        s1 += __shfl_xor(s1, off, 64);
        s2 += __shfl_xor(s2, off, 64);
    }
    __shared__ float l1[16], l2[16];
    const int wv = tid >> 6, lane = tid & 63;
    if (lane == 0) { l1[wv] = s1; l2[wv] = s2; }
    __syncthreads();
    float S1 = 0.f, S2 = 0.f;
    #pragma unroll
    for (int i = 0; i < 16; ++i) { S1 += l1[i]; S2 += l2[i]; }

    const float mu   = S1 * (1.0f / 512.0f);
    const float vr   = S2 * (1.0f / 512.0f) - mu * mu;
    const float rinv = rsqrtf(vr + LN_EPS);

    if (tid < 512) {
        const size_t o = (size_t)b * (KK * 512) + (size_t)k * 512;
        out[o + tid] = (val - mu) * rinv;
    }
}

// ---------------------------------------------------------------------------
extern "C" void kernel_launch(void* const* d_in, const int* in_sizes, int n_in,
                              void* d_out, int out_size, void* d_ws, size_t ws_size,
                              hipStream_t stream)
{
    const float* x       = (const float*)d_in[0];
    const float* centers = (const float*)d_in[1];
    const float* scale   = (const float*)d_in[2];
    const float* temp    = (const float*)d_in[3];
    float* out = (float*)d_out;

    int C = 64;   // needs 16.8 MB; ws is ~268 MB (round-5 fill counter)
    while (C > 2 && ((size_t)BB * C * KK * 512 + (size_t)BB * C * KK) * 4 > ws_size)
        C >>= 1;
    const int NT = (TT / C) / TILE;

    float* ws_wx = (float*)d_ws;
    float* ws_w  = ws_wx + (size_t)BB * C * KK * 512;

    dim3 g1(C, BB);
    lde_fused4<<<g1, 256, 0, stream>>>(x, centers, scale, temp, ws_wx, ws_w, C, NT);
    lde_final4<<<BB * KK, 1024, 0, stream>>>(ws_wx, ws_w, centers, out, C);
}